// Round 1
// 430.778 us; speedup vs baseline: 1.0039x; 1.0039x over previous
//
#include <hip/hip_runtime.h>
#include <hip/hip_bf16.h>

// Problem constants: B=4, C_IN=C_OUT=64, N=100000, K=6
#define BB   4
#define NN   100000
#define TOT  (BB * NN)          // 400000
#define KK   6
#define EPSV 1e-5f

using bf16   = __hip_bfloat16;
using ushort = unsigned short;
typedef __attribute__((ext_vector_type(8))) short  short8;   // 8 bf16 = 4 VGPRs
typedef __attribute__((ext_vector_type(4))) float  float4v;  // MFMA C/D

union U4S8 { uint4 u; short8 s; };

__device__ __forceinline__ unsigned f2bu(float f) {          // f32 -> raw bf16 RNE
    union { bf16 h; ushort u; } c; c.h = __float2bfloat16(f); return c.u;
}
__device__ __forceinline__ unsigned pk(float a, float b) {
    return f2bu(a) | (f2bu(b) << 16);
}
__device__ __forceinline__ float blo(unsigned x) {           // low bf16 -> f32
    union { unsigned u; float f; } c; c.u = x << 16; return c.f;
}
__device__ __forceinline__ float bhi(unsigned x) {           // high bf16 -> f32
    union { unsigned u; float f; } c; c.u = x & 0xFFFF0000u; return c.f;
}
__device__ __forceinline__ unsigned relu2(unsigned x) {      // relu on packed 2xbf16
    unsigned lo = (unsigned)(((int)(x << 16)) >> 31) & 0x0000FFFFu;
    unsigned hi = ((unsigned)(((int)x) >> 31)) << 16;
    return x & ~(lo | hi);
}
__device__ __forceinline__ int batch_base(int g) {           // (g/NN)*NN via compares
    return (g >= 3 * NN) ? 3 * NN : (g >= 2 * NN) ? 2 * NN : (g >= NN) ? NN : 0;
}

// ---------------------------------------------------------------------------
// wprep0: swizzle W0[o][c][2] into MFMA M-operand (B-role) fragments.
// Wf0[((t*2+s)*64+lane)*8+i] = W0[o=(t&3)*16+(lane&15)][c=s*32+(lane>>4)*8+i][t>>2]
// tiles t<4 -> u = x·We (center), t>=4 -> v = x·Wo (neighbor operator).
// ---------------------------------------------------------------------------
__global__ void wprep0_k(const float* __restrict__ W0, ushort* __restrict__ Wf0)
{
    int L = blockIdx.x * 256 + threadIdx.x;        // 8192
    if (L < 8192) {
        int i = L & 7, lane = (L >> 3) & 63, r = L >> 9;
        int s = r & 1, t = r >> 1;
        int o = (t & 3) * 16 + (lane & 15);
        int c = s * 32 + (lane >> 4) * 8 + i;
        Wf0[L] = f2bu(W0[o * 128 + c * 2 + (t >> 2)]);
    }
}

// ---------------------------------------------------------------------------
// xpose: x [B,C,N] f32 -> xT [B,N,C] bf16.
// ---------------------------------------------------------------------------
__global__ __launch_bounds__(256) void xpose_k(const float* __restrict__ x,
                                               ushort* __restrict__ xT)
{
    __shared__ float tile[64][65];
    const int b  = blockIdx.y;
    const int n0 = blockIdx.x * 64;
    const int tx = threadIdx.x & 63;
    const int ty = threadIdx.x >> 6;
    const float* xb = x + (size_t)b * 64 * NN;
    const int n = n0 + tx;
#pragma unroll
    for (int cc = 0; cc < 64; cc += 4) {
        const int c = cc + ty;
        tile[tx][c] = (n < NN) ? xb[(size_t)c * NN + n] : 0.f;
    }
    __syncthreads();
#pragma unroll
    for (int rr = 0; rr < 64; rr += 4) {
        const int nl = rr + ty;
        const int n2 = n0 + nl;
        if (n2 < NN) xT[((size_t)b * NN + n2) * 64 + tx] = (ushort)f2bu(tile[nl][tx]);
    }
}

// ---------------------------------------------------------------------------
// GEMM1: Uu[g][64] = xT[g]·We ; Uv[g][64] = xT[g]·Wo  (bf16 rows, 128 B).
// Streaming MFMA: weights in 64 VGPRs, A-frags direct global b128, no LDS.
// ---------------------------------------------------------------------------
__global__ __launch_bounds__(256, 3) void gemm1_k(
    const ushort* __restrict__ xT, const ushort* __restrict__ Wf,
    ushort* __restrict__ Uu, ushort* __restrict__ Uv)
{
    const int wave = threadIdx.x >> 6;
    const int lane = threadIdx.x & 63;
    const int col  = lane & 15;
    const int quad = lane >> 4;

    short8 wf[8][2];
#pragma unroll
    for (int t = 0; t < 8; ++t)
#pragma unroll
        for (int s = 0; s < 2; ++s)
            wf[t][s] = *(const short8*)(Wf + ((t * 2 + s) * 64 + lane) * 8);

    const int wid = blockIdx.x * 4 + wave;            // 2500 waves, 10 tiles each
    for (int tile = wid; tile < 25000; tile += 2500) {
        const size_t g0 = (size_t)tile * 16;
        const ushort* ar = xT + (g0 + col) * 64 + quad * 8;
        short8 p0 = *(const short8*)(ar);
        short8 p1 = *(const short8*)(ar + 32);

        float4v acc[8];
#pragma unroll
        for (int t = 0; t < 8; ++t) acc[t] = (float4v){0.f, 0.f, 0.f, 0.f};
#pragma unroll
        for (int t = 0; t < 8; ++t)
            acc[t] = __builtin_amdgcn_mfma_f32_16x16x32_bf16(wf[t][0], p0, acc[t], 0, 0, 0);
#pragma unroll
        for (int t = 0; t < 8; ++t)
            acc[t] = __builtin_amdgcn_mfma_f32_16x16x32_bf16(wf[t][1], p1, acc[t], 0, 0, 0);

        // D[row=quad*4+r -> ch][col -> point]
#pragma unroll
        for (int t = 0; t < 8; ++t) {
            uint2 d;
            d.x = pk(acc[t][0], acc[t][1]);
            d.y = pk(acc[t][2], acc[t][3]);
            ushort* base = (t < 4) ? Uu : Uv;
            *(uint2*)(base + (g0 + col) * 64 + (t & 3) * 16 + quad * 4) = d;
        }
    }
}

// ---------------------------------------------------------------------------
// gather1: h[g] = u[g] + sum_k v[nb_k].
// v2: latency-bound fix. 32 points/wave (4 groups of 8), grid 3125 (exact,
// no bounds checks). All 8 center loads batch-issued up front; neighbor
// indices loaded as 3x uint2 and software-pipelined ONE GROUP AHEAD so the
// idx->data dependency round-trip overlaps the previous group's data loads.
// Register pressure deliberately raised (~90 VGPR) so the full 12-load
// neighbor batch stays in flight (old version: 32 VGPR forced sub-batching).
// ---------------------------------------------------------------------------
__global__ __launch_bounds__(256, 4) void gather1_k(
    const ushort* __restrict__ Uu, const ushort* __restrict__ Uv,
    const int* __restrict__ neigh, ushort* __restrict__ hT,
    float* __restrict__ stats)
{
    __shared__ float red[4][128];
    const int wave = threadIdx.x >> 6;
    const int lane = threadIdx.x & 63;
    const int q    = lane >> 4;          // point-within-instruction
    const int cpos = lane & 15;          // channel chunk: ch = cpos*4 .. +3
    const int g0   = (blockIdx.x * 4 + wave) * 32;   // 3125 blocks * 128 pts = TOT

    float sA[4] = {0, 0, 0, 0}, sB[4] = {0, 0, 0, 0};

    // batch-issue ALL center-row loads (contiguous, 8 uint2) up front
    uint2 uu[4][2];
#pragma unroll
    for (int it = 0; it < 4; ++it)
#pragma unroll
        for (int i = 0; i < 2; ++i)
            uu[it][i] = *(const uint2*)(Uu + (size_t)(g0 + it * 8 + i * 4 + q) * 64 + cpos * 4);

    // group-0 neighbor indices (packed: 3 uint2 per point)
    const uint2* nbp = (const uint2*)neigh;
    uint2 nb[2][3], nbn[2][3];
#pragma unroll
    for (int i = 0; i < 2; ++i)
#pragma unroll
        for (int k = 0; k < 3; ++k)
            nb[i][k] = nbp[(size_t)(g0 + i * 4 + q) * 3 + k];

#pragma unroll
    for (int it = 0; it < 4; ++it) {
        const int gb = g0 + it * 8;
        int gp[2], bo[2];
        gp[0] = gb + q;     gp[1] = gb + 4 + q;
        bo[0] = batch_base(gp[0]);
        bo[1] = batch_base(gp[1]);

        // batch-issue the 12 neighbor-row loads (depends on nb, loaded 1 group ago)
        uint2 vv[2][6];
#pragma unroll
        for (int i = 0; i < 2; ++i) {
            vv[i][0] = *(const uint2*)(Uv + (size_t)(bo[i] + (int)nb[i][0].x) * 64 + cpos * 4);
            vv[i][1] = *(const uint2*)(Uv + (size_t)(bo[i] + (int)nb[i][0].y) * 64 + cpos * 4);
            vv[i][2] = *(const uint2*)(Uv + (size_t)(bo[i] + (int)nb[i][1].x) * 64 + cpos * 4);
            vv[i][3] = *(const uint2*)(Uv + (size_t)(bo[i] + (int)nb[i][1].y) * 64 + cpos * 4);
            vv[i][4] = *(const uint2*)(Uv + (size_t)(bo[i] + (int)nb[i][2].x) * 64 + cpos * 4);
            vv[i][5] = *(const uint2*)(Uv + (size_t)(bo[i] + (int)nb[i][2].y) * 64 + cpos * 4);
        }

        // prefetch NEXT group's neighbor indices — overlaps the vv latency
        if (it < 3) {
#pragma unroll
            for (int i = 0; i < 2; ++i)
#pragma unroll
                for (int k = 0; k < 3; ++k)
                    nbn[i][k] = nbp[(size_t)(gb + 8 + i * 4 + q) * 3 + k];
        }

        // consume + store + stats
#pragma unroll
        for (int i = 0; i < 2; ++i) {
            float h[4];
            h[0] = blo(uu[it][i].x); h[1] = bhi(uu[it][i].x);
            h[2] = blo(uu[it][i].y); h[3] = bhi(uu[it][i].y);
#pragma unroll
            for (int k = 0; k < 6; ++k) {
                h[0] += blo(vv[i][k].x); h[1] += bhi(vv[i][k].x);
                h[2] += blo(vv[i][k].y); h[3] += bhi(vv[i][k].y);
            }
            uint2 st;
            st.x = pk(h[0], h[1]);
            st.y = pk(h[2], h[3]);
            *(uint2*)(hT + (size_t)gp[i] * 64 + cpos * 4) = st;
#pragma unroll
            for (int j = 0; j < 4; ++j) {
                float rv = fmaxf(h[j], 0.f);
                sA[j] += rv;
                sB[j]  = fmaf(rv, rv, sB[j]);
            }
        }

#pragma unroll
        for (int i = 0; i < 2; ++i)
#pragma unroll
            for (int k = 0; k < 3; ++k)
                nb[i][k] = nbn[i][k];
    }

    // reduce across the 4 quarters (lane bits 4,5) — outside all load chains
#pragma unroll
    for (int d = 16; d < 64; d <<= 1)
#pragma unroll
        for (int j = 0; j < 4; ++j) {
            sA[j] += __shfl_xor(sA[j], d);
            sB[j] += __shfl_xor(sB[j], d);
        }
    if (q == 0) {
#pragma unroll
        for (int j = 0; j < 4; ++j) {
            red[wave][cpos * 4 + j]      = sA[j];
            red[wave][64 + cpos * 4 + j] = sB[j];
        }
    }
    __syncthreads();
    if (threadIdx.x < 128) {
        float v = red[0][threadIdx.x] + red[1][threadIdx.x]
                + red[2][threadIdx.x] + red[3][threadIdx.x];
        atomicAdd(&stats[threadIdx.x], v);   // 128 addrs/block, device scope
    }
}

// ---------------------------------------------------------------------------
// bnA: stats -> per-channel affine  rhat = a*relu(h) + b.   (1 block, ~2 us)
// ---------------------------------------------------------------------------
__global__ void bnA_k(const float* __restrict__ stats, const float* __restrict__ gamma,
                      const float* __restrict__ beta, float* __restrict__ ab)
{
    const int o = threadIdx.x;
    if (o < 64) {
        const float inv = 1.f / (float)TOT;
        float mean = stats[o] * inv;
        float var  = stats[64 + o] * inv - mean * mean;   // biased var (jnp.var)
        float a    = gamma[o] * rsqrtf(var + EPSV);
        ab[o]      = a;
        ab[64 + o] = fmaf(-a, mean, beta[o]);
    }
}

// ---------------------------------------------------------------------------
// bnB: parallel Wf1 swizzle (blocks 0..31) + bias dots (block 32).
// Wf1 = swizzled a_c*W1; bias[128] = [ sum_c b_c*We1[c][o] | sum_c b_c*Wo1 ].
// ---------------------------------------------------------------------------
__global__ __launch_bounds__(256) void bnB_k(
    const float* __restrict__ ab, const float* __restrict__ W1,
    ushort* __restrict__ Wf1, float* __restrict__ bias)
{
    if (blockIdx.x < 32) {
        int L = blockIdx.x * 256 + threadIdx.x;   // 8192
        int i = L & 7, lane = (L >> 3) & 63, r = L >> 9;
        int s = r & 1, t = r >> 1;
        int o = (t & 3) * 16 + (lane & 15);
        int c = s * 32 + (lane >> 4) * 8 + i;
        Wf1[L] = f2bu(ab[c] * W1[o * 128 + c * 2 + (t >> 2)]);
    } else if (threadIdx.x < 128) {
        const int part = threadIdx.x >> 6, o = threadIdx.x & 63;
        float s = 0.f;
#pragma unroll
        for (int c = 0; c < 64; ++c)
            s = fmaf(ab[64 + c], W1[o * 128 + c * 2 + part], s);
        bias[threadIdx.x] = s;
    }
}

// ---------------------------------------------------------------------------
// GEMM2: Up[g] = relu(hT[g])·We1' + biasE ; Uq[g] = relu(hT[g])·Wo1' + biasO.
// ---------------------------------------------------------------------------
__global__ __launch_bounds__(256, 3) void gemm2_k(
    const ushort* __restrict__ hT, const ushort* __restrict__ Wf,
    const float* __restrict__ bias, ushort* __restrict__ Up,
    ushort* __restrict__ Uq)
{
    const int wave = threadIdx.x >> 6;
    const int lane = threadIdx.x & 63;
    const int col  = lane & 15;
    const int quad = lane >> 4;

    short8 wf[8][2];
#pragma unroll
    for (int t = 0; t < 8; ++t)
#pragma unroll
        for (int s = 0; s < 2; ++s)
            wf[t][s] = *(const short8*)(Wf + ((t * 2 + s) * 64 + lane) * 8);

    float4v binit[8];
#pragma unroll
    for (int t = 0; t < 8; ++t)
#pragma unroll
        for (int r = 0; r < 4; ++r)
            binit[t][r] = bias[t * 16 + quad * 4 + r];

    const int wid = blockIdx.x * 4 + wave;
    for (int tile = wid; tile < 25000; tile += 2500) {
        const size_t g0 = (size_t)tile * 16;
        const ushort* ar = hT + (g0 + col) * 64 + quad * 8;
        U4S8 p0, p1;
        p0.u = *(const uint4*)(ar);
        p1.u = *(const uint4*)(ar + 32);
        p0.u.x = relu2(p0.u.x); p0.u.y = relu2(p0.u.y);
        p0.u.z = relu2(p0.u.z); p0.u.w = relu2(p0.u.w);
        p1.u.x = relu2(p1.u.x); p1.u.y = relu2(p1.u.y);
        p1.u.z = relu2(p1.u.z); p1.u.w = relu2(p1.u.w);

        float4v acc[8];
#pragma unroll
        for (int t = 0; t < 8; ++t) acc[t] = binit[t];
#pragma unroll
        for (int t = 0; t < 8; ++t)
            acc[t] = __builtin_amdgcn_mfma_f32_16x16x32_bf16(wf[t][0], p0.s, acc[t], 0, 0, 0);
#pragma unroll
        for (int t = 0; t < 8; ++t)
            acc[t] = __builtin_amdgcn_mfma_f32_16x16x32_bf16(wf[t][1], p1.s, acc[t], 0, 0, 0);

#pragma unroll
        for (int t = 0; t < 8; ++t) {
            uint2 d;
            d.x = pk(acc[t][0], acc[t][1]);
            d.y = pk(acc[t][2], acc[t][3]);
            ushort* base = (t < 4) ? Up : Uq;
            *(uint2*)(base + (g0 + col) * 64 + (t & 3) * 16 + quad * 4) = d;
        }
    }
}

// ---------------------------------------------------------------------------
// gather2: out[b][c][n] = relu( p[g] + sum_k q[nb_k] + hT[g] ).
// v2: same latency fix as gather1 — center loads (p, residual) batch-issued
// up front, packed uint2 neighbor indices pipelined one group ahead.
// ---------------------------------------------------------------------------
__global__ __launch_bounds__(256, 4) void gather2_k(
    const ushort* __restrict__ Up, const ushort* __restrict__ Uq,
    const ushort* __restrict__ hT, const int* __restrict__ neigh,
    float* __restrict__ out)
{
    __shared__ float ts[64][65];
    const int wave = threadIdx.x >> 6;
    const int lane = threadIdx.x & 63;
    const int q    = lane >> 4;
    const int cpos = lane & 15;
    const int g0   = blockIdx.x * 64;                 // 6250 blocks, exact
    const int gw   = g0 + wave * 16;                  // 16 pts/wave, 2 groups of 8

    // batch-issue ALL center loads for both groups (8 uint2)
    uint2 pp[2][2], rr[2][2];
#pragma unroll
    for (int it = 0; it < 2; ++it)
#pragma unroll
        for (int i = 0; i < 2; ++i) {
            const size_t a = (size_t)(gw + it * 8 + i * 4 + q) * 64 + cpos * 4;
            pp[it][i] = *(const uint2*)(Up + a);
            rr[it][i] = *(const uint2*)(hT + a);
        }

    // group-0 neighbor indices (packed)
    const uint2* nbp = (const uint2*)neigh;
    uint2 nb[2][3], nbn[2][3];
#pragma unroll
    for (int i = 0; i < 2; ++i)
#pragma unroll
        for (int k = 0; k < 3; ++k)
            nb[i][k] = nbp[(size_t)(gw + i * 4 + q) * 3 + k];

#pragma unroll
    for (int it = 0; it < 2; ++it) {
        const int gb = gw + it * 8;
        int gp[2], bo[2];
        gp[0] = gb + q;  gp[1] = gb + 4 + q;
        bo[0] = batch_base(gp[0]);
        bo[1] = batch_base(gp[1]);

        uint2 qq[2][6];
#pragma unroll
        for (int i = 0; i < 2; ++i) {
            qq[i][0] = *(const uint2*)(Uq + (size_t)(bo[i] + (int)nb[i][0].x) * 64 + cpos * 4);
            qq[i][1] = *(const uint2*)(Uq + (size_t)(bo[i] + (int)nb[i][0].y) * 64 + cpos * 4);
            qq[i][2] = *(const uint2*)(Uq + (size_t)(bo[i] + (int)nb[i][1].x) * 64 + cpos * 4);
            qq[i][3] = *(const uint2*)(Uq + (size_t)(bo[i] + (int)nb[i][1].y) * 64 + cpos * 4);
            qq[i][4] = *(const uint2*)(Uq + (size_t)(bo[i] + (int)nb[i][2].x) * 64 + cpos * 4);
            qq[i][5] = *(const uint2*)(Uq + (size_t)(bo[i] + (int)nb[i][2].y) * 64 + cpos * 4);
        }

        // prefetch next group's indices under the qq latency
        if (it == 0) {
#pragma unroll
            for (int i = 0; i < 2; ++i)
#pragma unroll
                for (int k = 0; k < 3; ++k)
                    nbn[i][k] = nbp[(size_t)(gb + 8 + i * 4 + q) * 3 + k];
        }

#pragma unroll
        for (int i = 0; i < 2; ++i) {
            float h[4];
            h[0] = blo(pp[it][i].x) + blo(rr[it][i].x); h[1] = bhi(pp[it][i].x) + bhi(rr[it][i].x);
            h[2] = blo(pp[it][i].y) + blo(rr[it][i].y); h[3] = bhi(pp[it][i].y) + bhi(rr[it][i].y);
#pragma unroll
            for (int k = 0; k < 6; ++k) {
                h[0] += blo(qq[i][k].x); h[1] += bhi(qq[i][k].x);
                h[2] += blo(qq[i][k].y); h[3] += bhi(qq[i][k].y);
            }
            const int pl = wave * 16 + it * 8 + i * 4 + q;
#pragma unroll
            for (int j = 0; j < 4; ++j)
                ts[cpos * 4 + j][pl] = fmaxf(h[j], 0.f);
        }

#pragma unroll
        for (int i = 0; i < 2; ++i)
#pragma unroll
            for (int k = 0; k < 3; ++k)
                nb[i][k] = nbn[i][k];
    }
    __syncthreads();

    // store transposed: o = wave*16+r rows, n = lane (per-lane batch split)
    const int g2  = g0 + lane;
    const int bo2 = batch_base(g2);
    const int b2  = (g2 >= 3 * NN) ? 3 : (g2 >= 2 * NN) ? 2 : (g2 >= NN) ? 1 : 0;
    const int n2  = g2 - bo2;
#pragma unroll
    for (int r = 0; r < 16; ++r) {
        const int o = wave * 16 + r;
        out[((size_t)b2 * 64 + o) * NN + n2] = ts[o][lane];
    }
}

// ---------------------------------------------------------------------------
// Workspace (bytes), total ~153.7 MB:
//   [0, 51.2M)        xT (xpose->gemm1), then hT (gather1->gemm2,gather2)
//   [51.2M, 102.4M)   Uu (gemm1->gather1), then Up (gemm2->gather2)
//   [102.4M, 153.6M)  Uv (gemm1->gather1), then Uq (gemm2->gather2)
//   153,600,000 stats[128] f32;  153,600,512 ab[128] f32;
//   153,601,024 Wf0 bf16[8192];  153,617,408 Wf1 bf16[8192];
//   153,633,792 bias[128] f32    (end 153,634,304)
// ---------------------------------------------------------------------------
extern "C" void kernel_launch(void* const* d_in, const int* in_sizes, int n_in,
                              void* d_out, int out_size, void* d_ws, size_t ws_size,
                              hipStream_t stream)
{
    const float* x     = (const float*)d_in[0];
    const int*   neigh = (const int*)d_in[1];
    const float* W0    = (const float*)d_in[2];
    const float* W1    = (const float*)d_in[3];
    const float* gamma = (const float*)d_in[4];
    const float* beta  = (const float*)d_in[5];
    float* out = (float*)d_out;

    char* ws = (char*)d_ws;
    ushort* xT    = (ushort*)(ws + 0);
    ushort* hT    = (ushort*)(ws + 0);
    ushort* Uu    = (ushort*)(ws + 51200000);
    ushort* Uv    = (ushort*)(ws + 102400000);
    ushort* Up    = Uu;
    ushort* Uq    = Uv;
    float*  stats = (float*)(ws + 153600000);
    float*  ab    = (float*)(ws + 153600512);
    ushort* Wf0   = (ushort*)(ws + 153601024);
    ushort* Wf1   = (ushort*)(ws + 153617408);
    float*  bias  = (float*)(ws + 153633792);

    hipMemsetAsync(stats, 0, 512, stream);
    wprep0_k<<<dim3(32), dim3(256), 0, stream>>>(W0, Wf0);
    xpose_k<<<dim3((NN + 63) / 64, BB), dim3(256), 0, stream>>>(x, xT);
    gemm1_k<<<dim3(625), dim3(256), 0, stream>>>(xT, Wf0, Uu, Uv);
    gather1_k<<<dim3(3125), dim3(256), 0, stream>>>(Uu, Uv, neigh, hT, stats);
    bnA_k<<<dim3(1), dim3(64), 0, stream>>>(stats, gamma, beta, ab);
    bnB_k<<<dim3(33), dim3(256), 0, stream>>>(ab, W1, Wf1, bias);
    gemm2_k<<<dim3(625), dim3(256), 0, stream>>>(hT, Wf1, bias, Up, Uq);
    gather2_k<<<dim3(TOT / 64), dim3(256), 0, stream>>>(Up, Uq, hT, neigh, out);
}